// Round 16
// baseline (793.724 us; speedup 1.0000x reference)
//
#include <hip/hip_runtime.h>
#include <math.h>

#define D_EMB 768
#define HEADS 12
#define HID   9216
#define BATCH 4
#define SEQ   1024
#define M_ROWS 4096

typedef __attribute__((ext_vector_type(8))) short bf16x8;
typedef __attribute__((ext_vector_type(4))) float f32x4;

__device__ __forceinline__ float b2f(unsigned short u) {
    return __uint_as_float(((unsigned)u) << 16);
}
__device__ __forceinline__ unsigned short f2b(float f) {
    unsigned u = __float_as_uint(f);
    u += 0x7fffu + ((u >> 16) & 1u);
    return (unsigned short)(u >> 16);
}

__device__ __forceinline__ void async_copy16(const void* g, void* l) {
    __builtin_amdgcn_global_load_lds(
        (const __attribute__((address_space(1))) void*)g,
        (__attribute__((address_space(3))) void*)l, 16, 0, 0);
}

enum { EPI_BF16 = 0, EPI_SCALE_BF16 = 1, EPI_BIAS_BF16 = 2,
       EPI_BIAS_GELU_BF16 = 3, EPI_BIAS_RES_F32 = 4, EPI_F32_PART = 5 };

// ---------------------------------------------------------------------------
// 8-phase 256x256 QKV GEMM (T3+T4+T2+T5) -- round-12/14 measured config
// (2-D grid: bm = blockIdx.x fast; XCD-chunked variant measured WORSE r15).
// BK=64, 512 thr / 8 waves, LDS 128 KB dynamic, XOR-swizzled both-sides,
// per-phase vmcnt(8) counted waits, region stage map q0..q3, setprio MFMA.
// ---------------------------------------------------------------------------
__global__ __launch_bounds__(512, 2)
void gemm_qkv8(const unsigned short* __restrict__ A,
               const unsigned short* __restrict__ B,
               unsigned short* __restrict__ Cq,
               unsigned short* __restrict__ Ck,
               unsigned short* __restrict__ Cv,
               const float* __restrict__ bq,
               const float* __restrict__ bk,
               const float* __restrict__ bv,
               int K, int lda, int ldb, int ldc)
{
    extern __shared__ unsigned short lds[];   // [2][A|B][256*64]
    const int tid = threadIdx.x;
    const int lane = tid & 63;
    const int wid = tid >> 6;
    const int wm = wid >> 2;        // 0..1
    const int wn = wid & 3;         // 0..3
    const int bm = blockIdx.x, bn = blockIdx.y;

    const int r = lane & 15, ks = lane >> 4;
    const int swz_src = (((lane & 7) ^ (lane >> 3)) * 8);
    const int l8 = lane * 8;

    const unsigned short* Ag = A + (long)(bm * 256) * lda;
    const unsigned short* Bg = B + (long)(bn * 256) * ldb;

    auto ldsA = [&](int buf) -> unsigned short* { return lds + buf * 32768; };
    auto ldsB = [&](int buf) -> unsigned short* { return lds + buf * 32768 + 16384; };

    auto stageA = [&](int buf, int reg, int kt) {
        unsigned short* base = ldsA(buf);
        #pragma unroll
        for (int i = 0; i < 2; i++) {
            const int idx = i * 64 + wid * 8;
            const int row = (reg ? 64 : 0) + (idx & 63) + ((idx >> 6) << 7);
            const unsigned short* src = Ag + (long)(row + (lane >> 3)) * lda
                                        + kt * 64 + swz_src;
            async_copy16(src, base + row * 64 + l8);
        }
    };
    auto stageB = [&](int buf, int reg, int kt) {
        unsigned short* base = ldsB(buf);
        #pragma unroll
        for (int i = 0; i < 2; i++) {
            const int idx = i * 64 + wid * 8;
            const int row = ((idx >> 5) << 6) + (reg ? 32 : 0) + (idx & 31);
            const unsigned short* src = Bg + (long)(row + (lane >> 3)) * ldb
                                        + kt * 64 + swz_src;
            async_copy16(src, base + row * 64 + l8);
        }
    };
    auto readA = [&](int buf, int m, int s) {
        const int row = wm * 128 + m * 16 + r;
        const int cg = (ks + s * 4) ^ (lane & 7);
        return *(const bf16x8*)&ldsA(buf)[row * 64 + cg * 8];
    };
    auto readB = [&](int buf, int n, int s) {
        const int row = wn * 64 + n * 16 + r;
        const int cg = (ks + s * 4) ^ (lane & 7);
        return *(const bf16x8*)&ldsB(buf)[row * 64 + cg * 8];
    };

    f32x4 acc[8][4] = {};
    const int nt = K >> 6;

    stageA(0, 0, 0); stageB(0, 0, 0); stageB(0, 1, 0); stageA(0, 1, 0);
    if (nt > 1) { stageA(1, 0, 1); stageB(1, 0, 1); }
    asm volatile("s_waitcnt vmcnt(4)" ::: "memory");
    __builtin_amdgcn_s_barrier();

    for (int t = 0; t < nt; t++) {
        const int buf = t & 1, obuf = buf ^ 1;
        #pragma unroll
        for (int q = 0; q < 4; q++) {
            const int mq = q >> 1, nq = q & 1;
            if (q > 0 || t > 0) {
                asm volatile("s_waitcnt vmcnt(8)" ::: "memory");
                __builtin_amdgcn_s_barrier();
            }
            if (q == 0)      { if (t + 1 < nt) stageB(obuf, 1, t + 1); }
            else if (q == 1) { if (t + 1 < nt) stageA(obuf, 1, t + 1); }
            else if (q == 2) { if (t + 2 < nt) stageA(buf, 0, t + 2); }
            else             { if (t + 2 < nt) stageB(buf, 0, t + 2); }

            bf16x8 af[4][2], bfv[2][2];
            #pragma unroll
            for (int mi = 0; mi < 4; mi++)
                #pragma unroll
                for (int s = 0; s < 2; s++)
                    af[mi][s] = readA(buf, mq * 4 + mi, s);
            #pragma unroll
            for (int ni = 0; ni < 2; ni++)
                #pragma unroll
                for (int s = 0; s < 2; s++)
                    bfv[ni][s] = readB(buf, nq * 2 + ni, s);

            __builtin_amdgcn_s_setprio(1);
            #pragma unroll
            for (int mi = 0; mi < 4; mi++)
                #pragma unroll
                for (int ni = 0; ni < 2; ni++)
                    #pragma unroll
                    for (int s = 0; s < 2; s++)
                        acc[mq * 4 + mi][nq * 2 + ni] =
                            __builtin_amdgcn_mfma_f32_16x16x32_bf16(
                                af[mi][s], bfv[ni][s],
                                acc[mq * 4 + mi][nq * 2 + ni], 0, 0, 0);
            __builtin_amdgcn_s_setprio(0);
        }
    }

    const int third = (bn * 256) / ldc;
    unsigned short* C = (third == 0) ? Cq : (third == 1) ? Ck : Cv;
    const float* bs = (third == 0) ? bq : (third == 1) ? bk : bv;
    #pragma unroll
    for (int m = 0; m < 8; m++) {
        const int row0 = bm * 256 + wm * 128 + m * 16 + ks * 4;
        #pragma unroll
        for (int n = 0; n < 4; n++) {
            const int cl = bn * 256 + wn * 64 + n * 16 + r - third * ldc;
            const float bsv = bs[cl];
            #pragma unroll
            for (int j = 0; j < 4; j++)
                C[(long)(row0 + j) * ldc + cl] = f2b(acc[m][n][j] + bsv);
        }
    }
}

// NT GEMM: 128x128 tile, 4 waves, 2-phase double-buffered LDS.
// SWAP=1: bm fast axis. XS=1: 1-D grid, chunked XCD swizzle (bz -> XCD bz%8).
// EPI_F32_PART: grid.z = K-splits of size ksplit writing partial buffers.
template<int EPI, int SWAP = 0, int XS = 0>
__global__ __launch_bounds__(256)
void gemm_bt(const unsigned short* __restrict__ A,
             const unsigned short* __restrict__ B,
             void* __restrict__ Cv,
             const float* __restrict__ bias,
             const float* __restrict__ resid,
             float scale, int K, int ksplit,
             int lda, int ldb, int ldc, int nh, int nbm, int nbn,
             long sAb, long sAh, long sBb, long sBh, long sCb, long sCh)
{
    __shared__ unsigned short As[2][128 * 32];
    __shared__ unsigned short Bs[2][128 * 32];

    int bm, bn, bz;
    if constexpr (XS) {
        const int lid = blockIdx.x;
        const int nb = nbm * nbn;
        const int xcd = lid & 7, j = lid >> 3;
        bz = xcd * ((4 * nh) >> 3) + j / nb;
        const int pos = j % nb;
        bm = pos / nbn;
        bn = pos % nbn;
    } else {
        bm = SWAP ? blockIdx.x : blockIdx.y;
        bn = SWAP ? blockIdx.y : blockIdx.x;
        bz = blockIdx.z;
    }

    int Kloop = K;
    const unsigned short* Ab;
    const unsigned short* Bb;
    long coff;
    if constexpr (EPI == EPI_F32_PART) {
        Ab = A + (long)bz * ksplit;
        Bb = B + (long)bz * ksplit;
        coff = (long)bz * sCb;
        Kloop = ksplit;
    } else {
        const int b = bz / nh, h = bz - b * nh;
        Ab = A + (long)b * sAb + (long)h * sAh;
        Bb = B + (long)b * sBb + (long)h * sBh;
        coff = (long)b * sCb + (long)h * sCh;
    }

    const int tid = threadIdx.x;
    const int c0 = tid, c1 = tid + 256;

    const unsigned short* Ap0 = Ab + (long)(bm * 128 + (c0 >> 2)) * lda + (c0 & 3) * 8;
    const unsigned short* Ap1 = Ab + (long)(bm * 128 + (c1 >> 2)) * lda + (c1 & 3) * 8;
    const unsigned short* Bp0 = Bb + (long)(bn * 128 + (c0 >> 2)) * ldb + (c0 & 3) * 8;
    const unsigned short* Bp1 = Bb + (long)(bn * 128 + (c1 >> 2)) * ldb + (c1 & 3) * 8;

    const int lane = tid & 63;
    const int wid = tid >> 6;
    const int wm = wid >> 1, wn = wid & 1;
    const int r = lane & 15, ks = lane >> 4;

    f32x4 acc[4][4] = {};

    async_copy16(Ap0, &As[0][c0 * 8]);
    async_copy16(Ap1, &As[0][c1 * 8]);
    async_copy16(Bp0, &Bs[0][c0 * 8]);
    async_copy16(Bp1, &Bs[0][c1 * 8]);
    Ap0 += 32; Ap1 += 32; Bp0 += 32; Bp1 += 32;
    __syncthreads();

    int cur = 0;
    for (int kt = 0; kt < Kloop; kt += 32) {
        if (kt + 32 < Kloop) {
            const int nxt = cur ^ 1;
            async_copy16(Ap0, &As[nxt][c0 * 8]);
            async_copy16(Ap1, &As[nxt][c1 * 8]);
            async_copy16(Bp0, &Bs[nxt][c0 * 8]);
            async_copy16(Bp1, &Bs[nxt][c1 * 8]);
            Ap0 += 32; Ap1 += 32; Bp0 += 32; Bp1 += 32;
        }

        bf16x8 af[4], bfr[4];
        #pragma unroll
        for (int m = 0; m < 4; m++)
            af[m] = *(const bf16x8*)&As[cur][(wm * 64 + m * 16 + r) * 32 + ks * 8];
        #pragma unroll
        for (int n = 0; n < 4; n++)
            bfr[n] = *(const bf16x8*)&Bs[cur][(wn * 64 + n * 16 + r) * 32 + ks * 8];

        #pragma unroll
        for (int m = 0; m < 4; m++)
            #pragma unroll
            for (int n = 0; n < 4; n++)
                acc[m][n] = __builtin_amdgcn_mfma_f32_16x16x32_bf16(
                    af[m], bfr[n], acc[m][n], 0, 0, 0);

        __syncthreads();
        cur ^= 1;
    }

    #pragma unroll
    for (int m = 0; m < 4; m++) {
        const int row0 = bm * 128 + wm * 64 + m * 16 + ks * 4;
        #pragma unroll
        for (int n = 0; n < 4; n++) {
            const int col = bn * 128 + wn * 64 + n * 16 + r;
            #pragma unroll
            for (int j = 0; j < 4; j++) {
                const int row = row0 + j;
                float v = acc[m][n][j];
                if constexpr (EPI == EPI_SCALE_BF16) v *= scale;
                if constexpr (EPI == EPI_BIAS_BF16 || EPI == EPI_BIAS_GELU_BF16 ||
                              EPI == EPI_BIAS_RES_F32) v += bias[col];
                if constexpr (EPI == EPI_BIAS_GELU_BF16)
                    v = 0.5f * v * (1.0f + erff(v * 0.70710678118654752f));
                if constexpr (EPI == EPI_BIAS_RES_F32) {
                    float* C = (float*)Cv;
                    C[coff + (long)row * ldc + col] = v + resid[(long)row * ldc + col];
                } else if constexpr (EPI == EPI_F32_PART) {
                    float* C = (float*)Cv;
                    C[coff + (long)row * ldc + col] = v;
                } else {
                    unsigned short* C = (unsigned short*)Cv;
                    C[coff + (long)row * ldc + col] = f2b(v);
                }
            }
        }
    }
}

// x2 += sum of nsp partials
__global__ __launch_bounds__(256)
void reduce_part(const f32x4* __restrict__ p, f32x4* __restrict__ x2,
                 int n4, int nsp)
{
    const int i = blockIdx.x * 256 + threadIdx.x;
    f32x4 a = x2[i];
    for (int s = 0; s < nsp; s++) {
        const f32x4 v = p[(long)s * n4 + i];
        a[0] += v[0]; a[1] += v[1]; a[2] += v[2]; a[3] += v[3];
    }
    x2[i] = a;
}

// f32 in[R][C] (column slice starting at col0) -> bf16 out[c][r], out stride R
__global__ __launch_bounds__(256)
void transpose_w(const float* __restrict__ in, unsigned short* __restrict__ out,
                 int R, int C, int col0)
{
    __shared__ float t[32][33];
    const int c0 = blockIdx.x * 32, r0 = blockIdx.y * 32;
    const int tx = threadIdx.x & 31, ty = threadIdx.x >> 5;
    #pragma unroll
    for (int i = 0; i < 4; i++)
        t[ty + i * 8][tx] = in[(long)(r0 + ty + i * 8) * C + col0 + c0 + tx];
    __syncthreads();
    #pragma unroll
    for (int i = 0; i < 4; i++)
        out[(long)(c0 + ty + i * 8) * R + r0 + tx] = f2b(t[tx][ty + i * 8]);
}

// fused 3-panel transpose: z selects (wq,wk,wv) -> wsl panel z
__global__ __launch_bounds__(256)
void transpose_w3(const float* __restrict__ wq, const float* __restrict__ wk,
                  const float* __restrict__ wv, unsigned short* __restrict__ wsl,
                  int NGl, int col0)
{
    __shared__ float t[32][33];
    const int z = blockIdx.z;
    const float* in = (z == 0) ? wq : (z == 1) ? wk : wv;
    unsigned short* out = wsl + (size_t)z * NGl * D_EMB;
    const int c0 = blockIdx.x * 32, r0 = blockIdx.y * 32;
    const int tx = threadIdx.x & 31, ty = threadIdx.x >> 5;
    #pragma unroll
    for (int i = 0; i < 4; i++)
        t[ty + i * 8][tx] = in[(long)(r0 + ty + i * 8) * HID + col0 + c0 + tx];
    __syncthreads();
    #pragma unroll
    for (int i = 0; i < 4; i++)
        out[(long)(c0 + ty + i * 8) * D_EMB + r0 + tx] = f2b(t[tx][ty + i * 8]);
}

// v [B,S,ng*768] bf16 -> vt [(b*ng+hl)*768 + d][1024] bf16
__global__ __launch_bounds__(256)
void transpose_v(const unsigned short* __restrict__ v, unsigned short* __restrict__ vt,
                 int ng)
{
    __shared__ unsigned short t[32][34];
    const int bz = blockIdx.z;
    const int b = bz / ng, hl = bz - b * ng;
    const int d0 = blockIdx.x * 32, s0 = blockIdx.y * 32;
    const int tx = threadIdx.x & 31, ty = threadIdx.x >> 5;
    const int ld = ng * D_EMB;
    const unsigned short* vin = v + (long)b * SEQ * ld + (long)hl * D_EMB;
    #pragma unroll
    for (int i = 0; i < 4; i++)
        t[ty + i * 8][tx] = vin[(long)(s0 + ty + i * 8) * ld + d0 + tx];
    __syncthreads();
    unsigned short* vo = vt + (long)bz * D_EMB * SEQ;
    #pragma unroll
    for (int i = 0; i < 4; i++)
        vo[(long)(d0 + ty + i * 8) * SEQ + s0 + tx] = t[tx][ty + i * 8];
}

// fused LN1 + x2 init: nx = LN(x)*g+b (bf16), x2 = x + bo (f32)
__global__ __launch_bounds__(256)
void ln_x2_kernel(const float* __restrict__ x, const float* __restrict__ g,
                  const float* __restrict__ bb, const float* __restrict__ bo,
                  unsigned short* __restrict__ out, float* __restrict__ x2)
{
    const int row = blockIdx.x;
    const float* xr = x + (long)row * D_EMB;
    const int t = threadIdx.x;
    float v0 = xr[t], v1 = xr[t + 256], v2 = xr[t + 512];
    float s = v0 + v1 + v2;
    float ss = v0 * v0 + v1 * v1 + v2 * v2;
    #pragma unroll
    for (int o = 32; o > 0; o >>= 1) {
        s += __shfl_down(s, o);
        ss += __shfl_down(ss, o);
    }
    __shared__ float red[8];
    __shared__ float mu_s, rs_s;
    const int wid = t >> 6;
    if ((t & 63) == 0) { red[wid] = s; red[4 + wid] = ss; }
    __syncthreads();
    if (t == 0) {
        float a = red[0] + red[1] + red[2] + red[3];
        float q = red[4] + red[5] + red[6] + red[7];
        float mu = a * (1.0f / D_EMB);
        float var = q * (1.0f / D_EMB) - mu * mu;
        mu_s = mu;
        rs_s = rsqrtf(var + 1e-5f);
    }
    __syncthreads();
    const float mu = mu_s, rs = rs_s;
    unsigned short* orow = out + (long)row * D_EMB;
    float* x2r = x2 + (long)row * D_EMB;
    orow[t]       = f2b((v0 - mu) * rs * g[t]       + bb[t]);
    orow[t + 256] = f2b((v1 - mu) * rs * g[t + 256] + bb[t + 256]);
    orow[t + 512] = f2b((v2 - mu) * rs * g[t + 512] + bb[t + 512]);
    x2r[t]        = v0 + bo[t];
    x2r[t + 256]  = v1 + bo[t + 256];
    x2r[t + 512]  = v2 + bo[t + 512];
}

// row layernorm: x f32 [rows,768] -> bf16 out
__global__ __launch_bounds__(256)
void ln_kernel(const float* __restrict__ x, const float* __restrict__ g,
               const float* __restrict__ bb, unsigned short* __restrict__ out)
{
    const int row = blockIdx.x;
    const float* xr = x + (long)row * D_EMB;
    const int t = threadIdx.x;
    float v0 = xr[t], v1 = xr[t + 256], v2 = xr[t + 512];
    float s = v0 + v1 + v2;
    float ss = v0 * v0 + v1 * v1 + v2 * v2;
    #pragma unroll
    for (int o = 32; o > 0; o >>= 1) {
        s += __shfl_down(s, o);
        ss += __shfl_down(ss, o);
    }
    __shared__ float red[8];
    __shared__ float mu_s, rs_s;
    const int wid = t >> 6;
    if ((t & 63) == 0) { red[wid] = s; red[4 + wid] = ss; }
    __syncthreads();
    if (t == 0) {
        float a = red[0] + red[1] + red[2] + red[3];
        float q = red[4] + red[5] + red[6] + red[7];
        float mu = a * (1.0f / D_EMB);
        float var = q * (1.0f / D_EMB) - mu * mu;
        mu_s = mu;
        rs_s = rsqrtf(var + 1e-5f);
    }
    __syncthreads();
    const float mu = mu_s, rs = rs_s;
    unsigned short* orow = out + (long)row * D_EMB;
    orow[t]       = f2b((v0 - mu) * rs * g[t]       + bb[t]);
    orow[t + 256] = f2b((v1 - mu) * rs * g[t + 256] + bb[t + 256]);
    orow[t + 512] = f2b((v2 - mu) * rs * g[t + 512] + bb[t + 512]);
}

// softmax over q (row index) per column, in-place on bf16 scores
__global__ __launch_bounds__(256)
void col_softmax(unsigned short* __restrict__ s)
{
    const long base = (long)blockIdx.y * ((long)SEQ * SEQ);
    const int t63 = threadIdx.x & 63;
    const int part = threadIdx.x >> 6;
    const int col = blockIdx.x * 64 + t63;
    unsigned short* p = s + base + col;
    const int q0 = part * 256;
    float m = -1e30f, sum = 0.0f;
    for (int q = q0; q < q0 + 256; q++) {
        float v = b2f(p[(long)q * SEQ]);
        float mn = fmaxf(m, v);
        sum = sum * __expf(m - mn) + __expf(v - mn);
        m = mn;
    }
    __shared__ float lm[4][64], ls[4][64];
    lm[part][t63] = m;
    ls[part][t63] = sum;
    __syncthreads();
    const float M = fmaxf(fmaxf(lm[0][t63], lm[1][t63]),
                          fmaxf(lm[2][t63], lm[3][t63]));
    const float S = ls[0][t63] * __expf(lm[0][t63] - M)
                  + ls[1][t63] * __expf(lm[1][t63] - M)
                  + ls[2][t63] * __expf(lm[2][t63] - M)
                  + ls[3][t63] * __expf(lm[3][t63] - M);
    const float inv = 1.0f / S;
    for (int q = q0; q < q0 + 256; q++) {
        float v = b2f(p[(long)q * SEQ]);
        p[(long)q * SEQ] = f2b(__expf(v - M) * inv);
    }
}

extern "C" void kernel_launch(void* const* d_in, const int* in_sizes, int n_in,
                              void* d_out, int out_size, void* d_ws, size_t ws_size,
                              hipStream_t stream)
{
    const float* x    = (const float*)d_in[0];
    const float* ln1g = (const float*)d_in[1];
    const float* ln1b = (const float*)d_in[2];
    const float* wq   = (const float*)d_in[3];
    const float* bq   = (const float*)d_in[4];
    const float* wk   = (const float*)d_in[5];
    const float* bk   = (const float*)d_in[6];
    const float* wv   = (const float*)d_in[7];
    const float* bv   = (const float*)d_in[8];
    const float* wo   = (const float*)d_in[9];
    const float* bo   = (const float*)d_in[10];
    const float* ln2g = (const float*)d_in[11];
    const float* ln2b = (const float*)d_in[12];
    const float* w1   = (const float*)d_in[13];
    const float* b1   = (const float*)d_in[14];
    const float* w2   = (const float*)d_in[15];
    const float* b2   = (const float*)d_in[16];
    float* out = (float*)d_out;

    auto a256 = [](size_t b) { return (b + 255) & ~(size_t)255; };

    auto plan_bytes = [&](int g) -> size_t {
        size_t o = 0;
        o += a256((size_t)D_EMB * D_EMB * 2);                    // w1T
        o += a256((size_t)D_EMB * D_EMB * 2);                    // w2T
        o += a256((size_t)M_ROWS * D_EMB * 2);                   // nx
        o += a256((size_t)M_ROWS * D_EMB * 2);                   // h1
        o += a256((size_t)M_ROWS * D_EMB * 4);                   // x2
        o += a256((size_t)3 * g * D_EMB * D_EMB * 2);            // wsl
        o += 3 * a256((size_t)M_ROWS * (size_t)g * D_EMB * 2);   // qg kg vtg
        size_t vr = (size_t)M_ROWS * (size_t)g * D_EMB * 2;
        size_t sc = (size_t)BATCH * g * SEQ * SEQ * 2;
        o += a256(vr > sc ? vr : sc);                            // vr/scg overlay
        return o;
    };
    const int cand[6] = {12, 6, 4, 3, 2, 1};
    int G = 1;
    for (int i = 0; i < 6; i++) {
        if (plan_bytes(cand[i]) <= ws_size) { G = cand[i]; break; }
    }
    const int NG = G * D_EMB;

    char* ws = (char*)d_ws;
    size_t off = 0;
    auto alloc = [&](size_t bytes) {
        void* p = ws + off;
        off += a256(bytes);
        return p;
    };
    unsigned short* w1T = (unsigned short*)alloc((size_t)D_EMB * D_EMB * 2);
    unsigned short* w2T = (unsigned short*)alloc((size_t)D_EMB * D_EMB * 2);
    unsigned short* nx  = (unsigned short*)alloc((size_t)M_ROWS * D_EMB * 2);
    unsigned short* h1  = (unsigned short*)alloc((size_t)M_ROWS * D_EMB * 2);
    float* x2           = (float*)alloc((size_t)M_ROWS * D_EMB * 4);
    unsigned short* wsl = (unsigned short*)alloc((size_t)3 * NG * D_EMB * 2);
    unsigned short* qg  = (unsigned short*)alloc((size_t)M_ROWS * NG * 2);  // later: ctx
    unsigned short* kg  = (unsigned short*)alloc((size_t)M_ROWS * NG * 2);  // later: WO partials
    unsigned short* vtg = (unsigned short*)alloc((size_t)M_ROWS * NG * 2);
    {
        size_t vr = (size_t)M_ROWS * NG * 2;
        size_t sc = (size_t)BATCH * G * SEQ * SEQ * 2;
        (void)alloc(vr > sc ? vr : sc);
    }
    unsigned short* vr  = vtg + (size_t)M_ROWS * NG;
    unsigned short* scg = vr;
    unsigned short* ctx = qg;

    // WO split-K partials in kg+vtg region; nsp=2 preferred (less reduce
    // traffic; 384 blocks still fill the GPU at ~3 blocks/CU occupancy).
    const size_t part_one = (size_t)M_ROWS * D_EMB * 4;
    const size_t avail = 2 * (size_t)M_ROWS * NG * 2;
    int nsp = 2;
    while (nsp > 1 && (size_t)nsp * part_one > avail) nsp >>= 1;
    while (nsp > 1 && (NG / nsp) % 32 != 0) nsp >>= 1;
    float* part = (float*)kg;

    const dim3 blk(256);
    const float scl = 0.03608439182435161f;  // 1/sqrt(768)
    const int nbh = BATCH * G;
    const bool xs_ok = (nbh % 8) == 0;

    hipFuncSetAttribute((const void*)gemm_qkv8,
                        hipFuncAttributeMaxDynamicSharedMemorySize, 131072);

    // fused LN1 + x2 = x + bo
    ln_x2_kernel<<<dim3(M_ROWS), blk, 0, stream>>>(x, ln1g, ln1b, bo, nx, x2);
    transpose_w<<<dim3(D_EMB / 32, D_EMB / 32), blk, 0, stream>>>(w1, w1T, D_EMB, D_EMB, 0);
    transpose_w<<<dim3(D_EMB / 32, D_EMB / 32), blk, 0, stream>>>(w2, w2T, D_EMB, D_EMB, 0);

    const int ngrp = HEADS / G;
    for (int g = 0; g < ngrp; g++) {
        const int h0 = g * G;
        // fused Q/K/V weight-panel transposes (one dispatch)
        transpose_w3<<<dim3(NG / 32, D_EMB / 32, 3), blk, 0, stream>>>(
            wq, wk, wv, wsl, NG, h0 * D_EMB);

        // fused QKV via 8-phase 256x256 kernel (2-D grid, round-14 config)
        gemm_qkv8<<<dim3(M_ROWS / 256, 3 * NG / 256, 1), dim3(512), 131072, stream>>>(
            nx, wsl, qg, kg, vr,
            bq + h0 * D_EMB, bk + h0 * D_EMB, bv + h0 * D_EMB,
            D_EMB, D_EMB, D_EMB, NG);
        transpose_v<<<dim3(D_EMB / 32, SEQ / 32, nbh), blk, 0, stream>>>(vr, vtg, G);

        // scores = q @ k^T / sqrt(768): 2-barrier 128^2 + XCD-chunked swizzle
        if (xs_ok) {
            gemm_bt<EPI_SCALE_BF16, 0, 1><<<dim3(nbh * 64, 1, 1), blk, 0, stream>>>(
                qg, kg, scg, nullptr, nullptr,
                scl, D_EMB, 0, NG, NG, SEQ, G, 8, 8,
                (long)SEQ * NG, D_EMB, (long)SEQ * NG, D_EMB,
                (long)G * SEQ * SEQ, (long)SEQ * SEQ);
        } else {
            gemm_bt<EPI_SCALE_BF16><<<dim3(SEQ / 128, SEQ / 128, nbh), blk, 0, stream>>>(
                qg, kg, scg, nullptr, nullptr,
                scl, D_EMB, 0, NG, NG, SEQ, G, 0, 0,
                (long)SEQ * NG, D_EMB, (long)SEQ * NG, D_EMB,
                (long)G * SEQ * SEQ, (long)SEQ * SEQ);
        }

        col_softmax<<<dim3(SEQ / 64, nbh), blk, 0, stream>>>(scg);

        // ctx = attn @ v (writes over qg): 2-barrier 128^2 + XCD swizzle
        if (xs_ok) {
            gemm_bt<EPI_BF16, 0, 1><<<dim3(nbh * 48, 1, 1), blk, 0, stream>>>(
                scg, vtg, ctx, nullptr, nullptr,
                1.0f, SEQ, 0, SEQ, SEQ, NG, G, 8, 6,
                (long)G * SEQ * SEQ, (long)SEQ * SEQ,
                (long)G * D_EMB * SEQ, (long)D_EMB * SEQ,
                (long)SEQ * NG, (long)D_EMB);
        } else {
            gemm_bt<EPI_BF16><<<dim3(D_EMB / 128, SEQ / 128, nbh), blk, 0, stream>>>(
                scg, vtg, ctx, nullptr, nullptr,
                1.0f, SEQ, 0, SEQ, SEQ, NG, G, 0, 0,
                (long)G * SEQ * SEQ, (long)SEQ * SEQ,
                (long)G * D_EMB * SEQ, (long)D_EMB * SEQ,
                (long)SEQ * NG, (long)D_EMB);
        }

        // WO split-K partials (SWAP grid: bm fastest -> woT panel L2 reuse)
        transpose_w<<<dim3(D_EMB / 32, NG / 32), blk, 0, stream>>>(
            wo + (long)h0 * D_EMB * D_EMB, wsl, NG, D_EMB, 0);
        gemm_bt<EPI_F32_PART, 1><<<dim3(M_ROWS / 128, D_EMB / 128, nsp), blk, 0, stream>>>(
            ctx, wsl, part, nullptr, nullptr,
            1.0f, NG, NG / nsp, NG, NG, D_EMB, 1, 0, 0,
            0, 0, 0, 0, (long)M_ROWS * D_EMB, 0);
        reduce_part<<<dim3(M_ROWS * D_EMB / 4 / 256), blk, 0, stream>>>(
            (const f32x4*)part, (f32x4*)x2, M_ROWS * D_EMB / 4, nsp);
    }

    ln_kernel<<<dim3(M_ROWS), blk, 0, stream>>>(x2, ln2g, ln2b, nx);

    gemm_bt<EPI_BIAS_GELU_BF16><<<dim3(D_EMB / 128, M_ROWS / 128, 1), blk, 0, stream>>>(
        nx, w1T, h1, b1, nullptr,
        1.0f, D_EMB, 0, D_EMB, D_EMB, D_EMB, 1, 0, 0, 0, 0, 0, 0, 0, 0);

    gemm_bt<EPI_BIAS_RES_F32><<<dim3(D_EMB / 128, M_ROWS / 128, 1), blk, 0, stream>>>(
        h1, w2T, out, b2, x2,
        1.0f, D_EMB, 0, D_EMB, D_EMB, D_EMB, 1, 0, 0, 0, 0, 0, 0, 0, 0);
}

// Round 17
// 775.093 us; speedup vs baseline: 1.0240x; 1.0240x over previous
//
#include <hip/hip_runtime.h>
#include <math.h>

#define D_EMB 768
#define HEADS 12
#define HID   9216
#define BATCH 4
#define SEQ   1024
#define M_ROWS 4096

typedef __attribute__((ext_vector_type(8))) short bf16x8;
typedef __attribute__((ext_vector_type(4))) float f32x4;

__device__ __forceinline__ float b2f(unsigned short u) {
    return __uint_as_float(((unsigned)u) << 16);
}
__device__ __forceinline__ unsigned short f2b(float f) {
    unsigned u = __float_as_uint(f);
    u += 0x7fffu + ((u >> 16) & 1u);
    return (unsigned short)(u >> 16);
}

__device__ __forceinline__ void async_copy16(const void* g, void* l) {
    __builtin_amdgcn_global_load_lds(
        (const __attribute__((address_space(1))) void*)g,
        (__attribute__((address_space(3))) void*)l, 16, 0, 0);
}

enum { EPI_BF16 = 0, EPI_SCALE_BF16 = 1, EPI_BIAS_BF16 = 2,
       EPI_BIAS_GELU_BF16 = 3, EPI_BIAS_RES_F32 = 4, EPI_F32_PART = 5 };

// ---------------------------------------------------------------------------
// 8-phase 256x256 QKV GEMM (T3+T4+T2+T5) -- round-12/14 measured config
// (2-D grid: bm = blockIdx.x fast; XCD-chunked variant measured WORSE r15).
// BK=64, 512 thr / 8 waves, LDS 128 KB dynamic, XOR-swizzled both-sides,
// per-phase vmcnt(8) counted waits, region stage map q0..q3, setprio MFMA.
// ---------------------------------------------------------------------------
__global__ __launch_bounds__(512, 2)
void gemm_qkv8(const unsigned short* __restrict__ A,
               const unsigned short* __restrict__ B,
               unsigned short* __restrict__ Cq,
               unsigned short* __restrict__ Ck,
               unsigned short* __restrict__ Cv,
               const float* __restrict__ bq,
               const float* __restrict__ bk,
               const float* __restrict__ bv,
               int K, int lda, int ldb, int ldc)
{
    extern __shared__ unsigned short lds[];   // [2][A|B][256*64]
    const int tid = threadIdx.x;
    const int lane = tid & 63;
    const int wid = tid >> 6;
    const int wm = wid >> 2;        // 0..1
    const int wn = wid & 3;         // 0..3
    const int bm = blockIdx.x, bn = blockIdx.y;

    const int r = lane & 15, ks = lane >> 4;
    const int swz_src = (((lane & 7) ^ (lane >> 3)) * 8);
    const int l8 = lane * 8;

    const unsigned short* Ag = A + (long)(bm * 256) * lda;
    const unsigned short* Bg = B + (long)(bn * 256) * ldb;

    auto ldsA = [&](int buf) -> unsigned short* { return lds + buf * 32768; };
    auto ldsB = [&](int buf) -> unsigned short* { return lds + buf * 32768 + 16384; };

    auto stageA = [&](int buf, int reg, int kt) {
        unsigned short* base = ldsA(buf);
        #pragma unroll
        for (int i = 0; i < 2; i++) {
            const int idx = i * 64 + wid * 8;
            const int row = (reg ? 64 : 0) + (idx & 63) + ((idx >> 6) << 7);
            const unsigned short* src = Ag + (long)(row + (lane >> 3)) * lda
                                        + kt * 64 + swz_src;
            async_copy16(src, base + row * 64 + l8);
        }
    };
    auto stageB = [&](int buf, int reg, int kt) {
        unsigned short* base = ldsB(buf);
        #pragma unroll
        for (int i = 0; i < 2; i++) {
            const int idx = i * 64 + wid * 8;
            const int row = ((idx >> 5) << 6) + (reg ? 32 : 0) + (idx & 31);
            const unsigned short* src = Bg + (long)(row + (lane >> 3)) * ldb
                                        + kt * 64 + swz_src;
            async_copy16(src, base + row * 64 + l8);
        }
    };
    auto readA = [&](int buf, int m, int s) {
        const int row = wm * 128 + m * 16 + r;
        const int cg = (ks + s * 4) ^ (lane & 7);
        return *(const bf16x8*)&ldsA(buf)[row * 64 + cg * 8];
    };
    auto readB = [&](int buf, int n, int s) {
        const int row = wn * 64 + n * 16 + r;
        const int cg = (ks + s * 4) ^ (lane & 7);
        return *(const bf16x8*)&ldsB(buf)[row * 64 + cg * 8];
    };

    f32x4 acc[8][4] = {};
    const int nt = K >> 6;

    stageA(0, 0, 0); stageB(0, 0, 0); stageB(0, 1, 0); stageA(0, 1, 0);
    if (nt > 1) { stageA(1, 0, 1); stageB(1, 0, 1); }
    asm volatile("s_waitcnt vmcnt(4)" ::: "memory");
    __builtin_amdgcn_s_barrier();

    for (int t = 0; t < nt; t++) {
        const int buf = t & 1, obuf = buf ^ 1;
        #pragma unroll
        for (int q = 0; q < 4; q++) {
            const int mq = q >> 1, nq = q & 1;
            if (q > 0 || t > 0) {
                asm volatile("s_waitcnt vmcnt(8)" ::: "memory");
                __builtin_amdgcn_s_barrier();
            }
            if (q == 0)      { if (t + 1 < nt) stageB(obuf, 1, t + 1); }
            else if (q == 1) { if (t + 1 < nt) stageA(obuf, 1, t + 1); }
            else if (q == 2) { if (t + 2 < nt) stageA(buf, 0, t + 2); }
            else             { if (t + 2 < nt) stageB(buf, 0, t + 2); }

            bf16x8 af[4][2], bfv[2][2];
            #pragma unroll
            for (int mi = 0; mi < 4; mi++)
                #pragma unroll
                for (int s = 0; s < 2; s++)
                    af[mi][s] = readA(buf, mq * 4 + mi, s);
            #pragma unroll
            for (int ni = 0; ni < 2; ni++)
                #pragma unroll
                for (int s = 0; s < 2; s++)
                    bfv[ni][s] = readB(buf, nq * 2 + ni, s);

            __builtin_amdgcn_s_setprio(1);
            #pragma unroll
            for (int mi = 0; mi < 4; mi++)
                #pragma unroll
                for (int ni = 0; ni < 2; ni++)
                    #pragma unroll
                    for (int s = 0; s < 2; s++)
                        acc[mq * 4 + mi][nq * 2 + ni] =
                            __builtin_amdgcn_mfma_f32_16x16x32_bf16(
                                af[mi][s], bfv[ni][s],
                                acc[mq * 4 + mi][nq * 2 + ni], 0, 0, 0);
            __builtin_amdgcn_s_setprio(0);
        }
    }

    const int third = (bn * 256) / ldc;
    unsigned short* C = (third == 0) ? Cq : (third == 1) ? Ck : Cv;
    const float* bs = (third == 0) ? bq : (third == 1) ? bk : bv;
    #pragma unroll
    for (int m = 0; m < 8; m++) {
        const int row0 = bm * 256 + wm * 128 + m * 16 + ks * 4;
        #pragma unroll
        for (int n = 0; n < 4; n++) {
            const int cl = bn * 256 + wn * 64 + n * 16 + r - third * ldc;
            const float bsv = bs[cl];
            #pragma unroll
            for (int j = 0; j < 4; j++)
                C[(long)(row0 + j) * ldc + cl] = f2b(acc[m][n][j] + bsv);
        }
    }
}

// NT GEMM: 128x128 tile, 4 waves, 2-phase double-buffered LDS.
// SWAP=1: bm fast axis. XS=1: 1-D grid, chunked XCD swizzle (bz -> XCD bz%8).
// EPI_F32_PART: grid.z = K-splits of size ksplit writing partial buffers.
template<int EPI, int SWAP = 0, int XS = 0>
__global__ __launch_bounds__(256)
void gemm_bt(const unsigned short* __restrict__ A,
             const unsigned short* __restrict__ B,
             void* __restrict__ Cv,
             const float* __restrict__ bias,
             const float* __restrict__ resid,
             float scale, int K, int ksplit,
             int lda, int ldb, int ldc, int nh, int nbm, int nbn,
             long sAb, long sAh, long sBb, long sBh, long sCb, long sCh)
{
    __shared__ unsigned short As[2][128 * 32];
    __shared__ unsigned short Bs[2][128 * 32];

    int bm, bn, bz;
    if constexpr (XS) {
        const int lid = blockIdx.x;
        const int nb = nbm * nbn;
        const int xcd = lid & 7, j = lid >> 3;
        bz = xcd * ((4 * nh) >> 3) + j / nb;
        const int pos = j % nb;
        bm = pos / nbn;
        bn = pos % nbn;
    } else {
        bm = SWAP ? blockIdx.x : blockIdx.y;
        bn = SWAP ? blockIdx.y : blockIdx.x;
        bz = blockIdx.z;
    }

    int Kloop = K;
    const unsigned short* Ab;
    const unsigned short* Bb;
    long coff;
    if constexpr (EPI == EPI_F32_PART) {
        Ab = A + (long)bz * ksplit;
        Bb = B + (long)bz * ksplit;
        coff = (long)bz * sCb;
        Kloop = ksplit;
    } else {
        const int b = bz / nh, h = bz - b * nh;
        Ab = A + (long)b * sAb + (long)h * sAh;
        Bb = B + (long)b * sBb + (long)h * sBh;
        coff = (long)b * sCb + (long)h * sCh;
    }

    const int tid = threadIdx.x;
    const int c0 = tid, c1 = tid + 256;

    const unsigned short* Ap0 = Ab + (long)(bm * 128 + (c0 >> 2)) * lda + (c0 & 3) * 8;
    const unsigned short* Ap1 = Ab + (long)(bm * 128 + (c1 >> 2)) * lda + (c1 & 3) * 8;
    const unsigned short* Bp0 = Bb + (long)(bn * 128 + (c0 >> 2)) * ldb + (c0 & 3) * 8;
    const unsigned short* Bp1 = Bb + (long)(bn * 128 + (c1 >> 2)) * ldb + (c1 & 3) * 8;

    const int lane = tid & 63;
    const int wid = tid >> 6;
    const int wm = wid >> 1, wn = wid & 1;
    const int r = lane & 15, ks = lane >> 4;

    f32x4 acc[4][4] = {};

    async_copy16(Ap0, &As[0][c0 * 8]);
    async_copy16(Ap1, &As[0][c1 * 8]);
    async_copy16(Bp0, &Bs[0][c0 * 8]);
    async_copy16(Bp1, &Bs[0][c1 * 8]);
    Ap0 += 32; Ap1 += 32; Bp0 += 32; Bp1 += 32;
    __syncthreads();

    int cur = 0;
    for (int kt = 0; kt < Kloop; kt += 32) {
        if (kt + 32 < Kloop) {
            const int nxt = cur ^ 1;
            async_copy16(Ap0, &As[nxt][c0 * 8]);
            async_copy16(Ap1, &As[nxt][c1 * 8]);
            async_copy16(Bp0, &Bs[nxt][c0 * 8]);
            async_copy16(Bp1, &Bs[nxt][c1 * 8]);
            Ap0 += 32; Ap1 += 32; Bp0 += 32; Bp1 += 32;
        }

        bf16x8 af[4], bfr[4];
        #pragma unroll
        for (int m = 0; m < 4; m++)
            af[m] = *(const bf16x8*)&As[cur][(wm * 64 + m * 16 + r) * 32 + ks * 8];
        #pragma unroll
        for (int n = 0; n < 4; n++)
            bfr[n] = *(const bf16x8*)&Bs[cur][(wn * 64 + n * 16 + r) * 32 + ks * 8];

        #pragma unroll
        for (int m = 0; m < 4; m++)
            #pragma unroll
            for (int n = 0; n < 4; n++)
                acc[m][n] = __builtin_amdgcn_mfma_f32_16x16x32_bf16(
                    af[m], bfr[n], acc[m][n], 0, 0, 0);

        __syncthreads();
        cur ^= 1;
    }

    #pragma unroll
    for (int m = 0; m < 4; m++) {
        const int row0 = bm * 128 + wm * 64 + m * 16 + ks * 4;
        #pragma unroll
        for (int n = 0; n < 4; n++) {
            const int col = bn * 128 + wn * 64 + n * 16 + r;
            #pragma unroll
            for (int j = 0; j < 4; j++) {
                const int row = row0 + j;
                float v = acc[m][n][j];
                if constexpr (EPI == EPI_SCALE_BF16) v *= scale;
                if constexpr (EPI == EPI_BIAS_BF16 || EPI == EPI_BIAS_GELU_BF16 ||
                              EPI == EPI_BIAS_RES_F32) v += bias[col];
                if constexpr (EPI == EPI_BIAS_GELU_BF16)
                    v = 0.5f * v * (1.0f + erff(v * 0.70710678118654752f));
                if constexpr (EPI == EPI_BIAS_RES_F32) {
                    float* C = (float*)Cv;
                    C[coff + (long)row * ldc + col] = v + resid[(long)row * ldc + col];
                } else if constexpr (EPI == EPI_F32_PART) {
                    float* C = (float*)Cv;
                    C[coff + (long)row * ldc + col] = v;
                } else {
                    unsigned short* C = (unsigned short*)Cv;
                    C[coff + (long)row * ldc + col] = f2b(v);
                }
            }
        }
    }
}

// x2 += sum of nsp partials
__global__ __launch_bounds__(256)
void reduce_part(const f32x4* __restrict__ p, f32x4* __restrict__ x2,
                 int n4, int nsp)
{
    const int i = blockIdx.x * 256 + threadIdx.x;
    f32x4 a = x2[i];
    for (int s = 0; s < nsp; s++) {
        const f32x4 v = p[(long)s * n4 + i];
        a[0] += v[0]; a[1] += v[1]; a[2] += v[2]; a[3] += v[3];
    }
    x2[i] = a;
}

// f32 in[R][C] (column slice starting at col0) -> bf16 out[c][r], out stride R
__global__ __launch_bounds__(256)
void transpose_w(const float* __restrict__ in, unsigned short* __restrict__ out,
                 int R, int C, int col0)
{
    __shared__ float t[32][33];
    const int c0 = blockIdx.x * 32, r0 = blockIdx.y * 32;
    const int tx = threadIdx.x & 31, ty = threadIdx.x >> 5;
    #pragma unroll
    for (int i = 0; i < 4; i++)
        t[ty + i * 8][tx] = in[(long)(r0 + ty + i * 8) * C + col0 + c0 + tx];
    __syncthreads();
    #pragma unroll
    for (int i = 0; i < 4; i++)
        out[(long)(c0 + ty + i * 8) * R + r0 + tx] = f2b(t[tx][ty + i * 8]);
}

// fused 3-panel transpose: z selects (wq,wk,wv) -> wsl panel z
__global__ __launch_bounds__(256)
void transpose_w3(const float* __restrict__ wq, const float* __restrict__ wk,
                  const float* __restrict__ wv, unsigned short* __restrict__ wsl,
                  int NGl, int col0)
{
    __shared__ float t[32][33];
    const int z = blockIdx.z;
    const float* in = (z == 0) ? wq : (z == 1) ? wk : wv;
    unsigned short* out = wsl + (size_t)z * NGl * D_EMB;
    const int c0 = blockIdx.x * 32, r0 = blockIdx.y * 32;
    const int tx = threadIdx.x & 31, ty = threadIdx.x >> 5;
    #pragma unroll
    for (int i = 0; i < 4; i++)
        t[ty + i * 8][tx] = in[(long)(r0 + ty + i * 8) * HID + col0 + c0 + tx];
    __syncthreads();
    #pragma unroll
    for (int i = 0; i < 4; i++)
        out[(long)(c0 + ty + i * 8) * D_EMB + r0 + tx] = f2b(t[tx][ty + i * 8]);
}

// v [B,S,ng*768] bf16 -> vt [(b*ng+hl)*768 + d][1024] bf16
__global__ __launch_bounds__(256)
void transpose_v(const unsigned short* __restrict__ v, unsigned short* __restrict__ vt,
                 int ng)
{
    __shared__ unsigned short t[32][34];
    const int bz = blockIdx.z;
    const int b = bz / ng, hl = bz - b * ng;
    const int d0 = blockIdx.x * 32, s0 = blockIdx.y * 32;
    const int tx = threadIdx.x & 31, ty = threadIdx.x >> 5;
    const int ld = ng * D_EMB;
    const unsigned short* vin = v + (long)b * SEQ * ld + (long)hl * D_EMB;
    #pragma unroll
    for (int i = 0; i < 4; i++)
        t[ty + i * 8][tx] = vin[(long)(s0 + ty + i * 8) * ld + d0 + tx];
    __syncthreads();
    unsigned short* vo = vt + (long)bz * D_EMB * SEQ;
    #pragma unroll
    for (int i = 0; i < 4; i++)
        vo[(long)(d0 + ty + i * 8) * SEQ + s0 + tx] = t[tx][ty + i * 8];
}

// fused LN1 + x2 init: nx = LN(x)*g+b (bf16), x2 = x + bo (f32)
__global__ __launch_bounds__(256)
void ln_x2_kernel(const float* __restrict__ x, const float* __restrict__ g,
                  const float* __restrict__ bb, const float* __restrict__ bo,
                  unsigned short* __restrict__ out, float* __restrict__ x2)
{
    const int row = blockIdx.x;
    const float* xr = x + (long)row * D_EMB;
    const int t = threadIdx.x;
    float v0 = xr[t], v1 = xr[t + 256], v2 = xr[t + 512];
    float s = v0 + v1 + v2;
    float ss = v0 * v0 + v1 * v1 + v2 * v2;
    #pragma unroll
    for (int o = 32; o > 0; o >>= 1) {
        s += __shfl_down(s, o);
        ss += __shfl_down(ss, o);
    }
    __shared__ float red[8];
    __shared__ float mu_s, rs_s;
    const int wid = t >> 6;
    if ((t & 63) == 0) { red[wid] = s; red[4 + wid] = ss; }
    __syncthreads();
    if (t == 0) {
        float a = red[0] + red[1] + red[2] + red[3];
        float q = red[4] + red[5] + red[6] + red[7];
        float mu = a * (1.0f / D_EMB);
        float var = q * (1.0f / D_EMB) - mu * mu;
        mu_s = mu;
        rs_s = rsqrtf(var + 1e-5f);
    }
    __syncthreads();
    const float mu = mu_s, rs = rs_s;
    unsigned short* orow = out + (long)row * D_EMB;
    float* x2r = x2 + (long)row * D_EMB;
    orow[t]       = f2b((v0 - mu) * rs * g[t]       + bb[t]);
    orow[t + 256] = f2b((v1 - mu) * rs * g[t + 256] + bb[t + 256]);
    orow[t + 512] = f2b((v2 - mu) * rs * g[t + 512] + bb[t + 512]);
    x2r[t]        = v0 + bo[t];
    x2r[t + 256]  = v1 + bo[t + 256];
    x2r[t + 512]  = v2 + bo[t + 512];
}

// row layernorm: x f32 [rows,768] -> bf16 out
__global__ __launch_bounds__(256)
void ln_kernel(const float* __restrict__ x, const float* __restrict__ g,
               const float* __restrict__ bb, unsigned short* __restrict__ out)
{
    const int row = blockIdx.x;
    const float* xr = x + (long)row * D_EMB;
    const int t = threadIdx.x;
    float v0 = xr[t], v1 = xr[t + 256], v2 = xr[t + 512];
    float s = v0 + v1 + v2;
    float ss = v0 * v0 + v1 * v1 + v2 * v2;
    #pragma unroll
    for (int o = 32; o > 0; o >>= 1) {
        s += __shfl_down(s, o);
        ss += __shfl_down(ss, o);
    }
    __shared__ float red[8];
    __shared__ float mu_s, rs_s;
    const int wid = t >> 6;
    if ((t & 63) == 0) { red[wid] = s; red[4 + wid] = ss; }
    __syncthreads();
    if (t == 0) {
        float a = red[0] + red[1] + red[2] + red[3];
        float q = red[4] + red[5] + red[6] + red[7];
        float mu = a * (1.0f / D_EMB);
        float var = q * (1.0f / D_EMB) - mu * mu;
        mu_s = mu;
        rs_s = rsqrtf(var + 1e-5f);
    }
    __syncthreads();
    const float mu = mu_s, rs = rs_s;
    unsigned short* orow = out + (long)row * D_EMB;
    orow[t]       = f2b((v0 - mu) * rs * g[t]       + bb[t]);
    orow[t + 256] = f2b((v1 - mu) * rs * g[t + 256] + bb[t + 256]);
    orow[t + 512] = f2b((v2 - mu) * rs * g[t + 512] + bb[t + 512]);
}

// softmax over q (row index) per column, in-place on bf16 scores
__global__ __launch_bounds__(256)
void col_softmax(unsigned short* __restrict__ s)
{
    const long base = (long)blockIdx.y * ((long)SEQ * SEQ);
    const int t63 = threadIdx.x & 63;
    const int part = threadIdx.x >> 6;
    const int col = blockIdx.x * 64 + t63;
    unsigned short* p = s + base + col;
    const int q0 = part * 256;
    float m = -1e30f, sum = 0.0f;
    for (int q = q0; q < q0 + 256; q++) {
        float v = b2f(p[(long)q * SEQ]);
        float mn = fmaxf(m, v);
        sum = sum * __expf(m - mn) + __expf(v - mn);
        m = mn;
    }
    __shared__ float lm[4][64], ls[4][64];
    lm[part][t63] = m;
    ls[part][t63] = sum;
    __syncthreads();
    const float M = fmaxf(fmaxf(lm[0][t63], lm[1][t63]),
                          fmaxf(lm[2][t63], lm[3][t63]));
    const float S = ls[0][t63] * __expf(lm[0][t63] - M)
                  + ls[1][t63] * __expf(lm[1][t63] - M)
                  + ls[2][t63] * __expf(lm[2][t63] - M)
                  + ls[3][t63] * __expf(lm[3][t63] - M);
    const float inv = 1.0f / S;
    for (int q = q0; q < q0 + 256; q++) {
        float v = b2f(p[(long)q * SEQ]);
        p[(long)q * SEQ] = f2b(__expf(v - M) * inv);
    }
}

extern "C" void kernel_launch(void* const* d_in, const int* in_sizes, int n_in,
                              void* d_out, int out_size, void* d_ws, size_t ws_size,
                              hipStream_t stream)
{
    const float* x    = (const float*)d_in[0];
    const float* ln1g = (const float*)d_in[1];
    const float* ln1b = (const float*)d_in[2];
    const float* wq   = (const float*)d_in[3];
    const float* bq   = (const float*)d_in[4];
    const float* wk   = (const float*)d_in[5];
    const float* bk   = (const float*)d_in[6];
    const float* wv   = (const float*)d_in[7];
    const float* bv   = (const float*)d_in[8];
    const float* wo   = (const float*)d_in[9];
    const float* bo   = (const float*)d_in[10];
    const float* ln2g = (const float*)d_in[11];
    const float* ln2b = (const float*)d_in[12];
    const float* w1   = (const float*)d_in[13];
    const float* b1   = (const float*)d_in[14];
    const float* w2   = (const float*)d_in[15];
    const float* b2   = (const float*)d_in[16];
    float* out = (float*)d_out;

    auto a256 = [](size_t b) { return (b + 255) & ~(size_t)255; };

    auto plan_bytes = [&](int g) -> size_t {
        size_t o = 0;
        o += a256((size_t)D_EMB * D_EMB * 2);                    // w1T
        o += a256((size_t)D_EMB * D_EMB * 2);                    // w2T
        o += a256((size_t)M_ROWS * D_EMB * 2);                   // nx
        o += a256((size_t)M_ROWS * D_EMB * 2);                   // h1
        o += a256((size_t)M_ROWS * D_EMB * 4);                   // x2
        o += a256((size_t)3 * g * D_EMB * D_EMB * 2);            // wsl
        o += 3 * a256((size_t)M_ROWS * (size_t)g * D_EMB * 2);   // qg kg vtg
        size_t vr = (size_t)M_ROWS * (size_t)g * D_EMB * 2;
        size_t sc = (size_t)BATCH * g * SEQ * SEQ * 2;
        o += a256(vr > sc ? vr : sc);                            // vr/scg overlay
        return o;
    };
    const int cand[6] = {12, 6, 4, 3, 2, 1};
    int G = 1;
    for (int i = 0; i < 6; i++) {
        if (plan_bytes(cand[i]) <= ws_size) { G = cand[i]; break; }
    }
    const int NG = G * D_EMB;

    char* ws = (char*)d_ws;
    size_t off = 0;
    auto alloc = [&](size_t bytes) {
        void* p = ws + off;
        off += a256(bytes);
        return p;
    };
    unsigned short* w1T = (unsigned short*)alloc((size_t)D_EMB * D_EMB * 2);
    unsigned short* w2T = (unsigned short*)alloc((size_t)D_EMB * D_EMB * 2);
    unsigned short* nx  = (unsigned short*)alloc((size_t)M_ROWS * D_EMB * 2);
    unsigned short* h1  = (unsigned short*)alloc((size_t)M_ROWS * D_EMB * 2);
    float* x2           = (float*)alloc((size_t)M_ROWS * D_EMB * 4);
    unsigned short* wsl = (unsigned short*)alloc((size_t)3 * NG * D_EMB * 2);
    unsigned short* qg  = (unsigned short*)alloc((size_t)M_ROWS * NG * 2);  // later: ctx
    unsigned short* kg  = (unsigned short*)alloc((size_t)M_ROWS * NG * 2);  // later: WO partials
    unsigned short* vtg = (unsigned short*)alloc((size_t)M_ROWS * NG * 2);
    {
        size_t vr = (size_t)M_ROWS * NG * 2;
        size_t sc = (size_t)BATCH * G * SEQ * SEQ * 2;
        (void)alloc(vr > sc ? vr : sc);
    }
    unsigned short* vr  = vtg + (size_t)M_ROWS * NG;
    unsigned short* scg = vr;
    unsigned short* ctx = qg;

    // WO split-K partials in kg+vtg region; nsp=4 (measured best r14/r15 —
    // nsp=2 regressed ~18us: 384 blocks under-fills, tail-bound).
    const size_t part_one = (size_t)M_ROWS * D_EMB * 4;
    const size_t avail = 2 * (size_t)M_ROWS * NG * 2;
    int nsp = 4;
    while (nsp > 1 && (size_t)nsp * part_one > avail) nsp >>= 1;
    while (nsp > 1 && (NG / nsp) % 32 != 0) nsp >>= 1;
    float* part = (float*)kg;

    const dim3 blk(256);
    const float scl = 0.03608439182435161f;  // 1/sqrt(768)
    const int nbh = BATCH * G;
    const bool xs_ok = (nbh % 8) == 0;

    hipFuncSetAttribute((const void*)gemm_qkv8,
                        hipFuncAttributeMaxDynamicSharedMemorySize, 131072);

    // fused LN1 + x2 = x + bo
    ln_x2_kernel<<<dim3(M_ROWS), blk, 0, stream>>>(x, ln1g, ln1b, bo, nx, x2);
    transpose_w<<<dim3(D_EMB / 32, D_EMB / 32), blk, 0, stream>>>(w1, w1T, D_EMB, D_EMB, 0);
    transpose_w<<<dim3(D_EMB / 32, D_EMB / 32), blk, 0, stream>>>(w2, w2T, D_EMB, D_EMB, 0);

    const int ngrp = HEADS / G;
    for (int g = 0; g < ngrp; g++) {
        const int h0 = g * G;
        // fused Q/K/V weight-panel transposes (one dispatch)
        transpose_w3<<<dim3(NG / 32, D_EMB / 32, 3), blk, 0, stream>>>(
            wq, wk, wv, wsl, NG, h0 * D_EMB);

        // fused QKV via 8-phase 256x256 kernel (2-D grid, round-14 config)
        gemm_qkv8<<<dim3(M_ROWS / 256, 3 * NG / 256, 1), dim3(512), 131072, stream>>>(
            nx, wsl, qg, kg, vr,
            bq + h0 * D_EMB, bk + h0 * D_EMB, bv + h0 * D_EMB,
            D_EMB, D_EMB, D_EMB, NG);
        transpose_v<<<dim3(D_EMB / 32, SEQ / 32, nbh), blk, 0, stream>>>(vr, vtg, G);

        // scores = q @ k^T / sqrt(768): 2-barrier 128^2 + XCD-chunked swizzle
        if (xs_ok) {
            gemm_bt<EPI_SCALE_BF16, 0, 1><<<dim3(nbh * 64, 1, 1), blk, 0, stream>>>(
                qg, kg, scg, nullptr, nullptr,
                scl, D_EMB, 0, NG, NG, SEQ, G, 8, 8,
                (long)SEQ * NG, D_EMB, (long)SEQ * NG, D_EMB,
                (long)G * SEQ * SEQ, (long)SEQ * SEQ);
        } else {
            gemm_bt<EPI_SCALE_BF16><<<dim3(SEQ / 128, SEQ / 128, nbh), blk, 0, stream>>>(
                qg, kg, scg, nullptr, nullptr,
                scl, D_EMB, 0, NG, NG, SEQ, G, 0, 0,
                (long)SEQ * NG, D_EMB, (long)SEQ * NG, D_EMB,
                (long)G * SEQ * SEQ, (long)SEQ * SEQ);
        }

        col_softmax<<<dim3(SEQ / 64, nbh), blk, 0, stream>>>(scg);

        // ctx = attn @ v (writes over qg): 2-barrier 128^2 + XCD swizzle
        if (xs_ok) {
            gemm_bt<EPI_BF16, 0, 1><<<dim3(nbh * 48, 1, 1), blk, 0, stream>>>(
                scg, vtg, ctx, nullptr, nullptr,
                1.0f, SEQ, 0, SEQ, SEQ, NG, G, 8, 6,
                (long)G * SEQ * SEQ, (long)SEQ * SEQ,
                (long)G * D_EMB * SEQ, (long)D_EMB * SEQ,
                (long)SEQ * NG, (long)D_EMB);
        } else {
            gemm_bt<EPI_BF16><<<dim3(D_EMB / 128, SEQ / 128, nbh), blk, 0, stream>>>(
                scg, vtg, ctx, nullptr, nullptr,
                1.0f, SEQ, 0, SEQ, SEQ, NG, G, 0, 0,
                (long)G * SEQ * SEQ, (long)SEQ * SEQ,
                (long)G * D_EMB * SEQ, (long)D_EMB * SEQ,
                (long)SEQ * NG, (long)D_EMB);
        }

        // WO split-K partials (SWAP grid: bm fastest -> woT panel L2 reuse)
        transpose_w<<<dim3(D_EMB / 32, NG / 32), blk, 0, stream>>>(
            wo + (long)h0 * D_EMB * D_EMB, wsl, NG, D_EMB, 0);
        gemm_bt<EPI_F32_PART, 1><<<dim3(M_ROWS / 128, D_EMB / 128, nsp), blk, 0, stream>>>(
            ctx, wsl, part, nullptr, nullptr,
            1.0f, NG, NG / nsp, NG, NG, D_EMB, 1, 0, 0,
            0, 0, 0, 0, (long)M_ROWS * D_EMB, 0);
        reduce_part<<<dim3(M_ROWS * D_EMB / 4 / 256), blk, 0, stream>>>(
            (const f32x4*)part, (f32x4*)x2, M_ROWS * D_EMB / 4, nsp);
    }

    ln_kernel<<<dim3(M_ROWS), blk, 0, stream>>>(x2, ln2g, ln2b, nx);

    gemm_bt<EPI_BIAS_GELU_BF16><<<dim3(D_EMB / 128, M_ROWS / 128, 1), blk, 0, stream>>>(
        nx, w1T, h1, b1, nullptr,
        1.0f, D_EMB, 0, D_EMB, D_EMB, D_EMB, 1, 0, 0, 0, 0, 0, 0, 0, 0);

    gemm_bt<EPI_BIAS_RES_F32><<<dim3(D_EMB / 128, M_ROWS / 128, 1), blk, 0, stream>>>(
        h1, w2T, out, b2, x2,
        1.0f, D_EMB, 0, D_EMB, D_EMB, D_EMB, 1, 0, 0, 0, 0, 0, 0, 0, 0);
}